// Round 19
// baseline (742.548 us; speedup 1.0000x reference)
//
#include <hip/hip_runtime.h>
#include <math.h>

// ---------------- constants ----------------
#define NTOK   8192
#define INDIM  1024
#define NHEAD  8
#define N1     8282      // tokens incl cls (91*91 + 1)
#define NP     8448      // padded token count inside attention
#define PAD    166
#define LCH    33        // tokens per landmark chunk
#define SCALE  0.125f
#define HS     91
#define KS3    22        // split-K for fused S3/PV flash kernel
#define KC3    (NP / KS3)   // 384 tokens per block (6 chunks of 64)

typedef __attribute__((ext_vector_type(8))) _Float16 half8;
typedef __attribute__((ext_vector_type(8))) short short8;
typedef __attribute__((ext_vector_type(4))) float f32x4;
typedef unsigned short ushort_t;

#define GPTR(p) ((const __attribute__((address_space(1))) void*)(p))
#define LPTR(p) ((__attribute__((address_space(3))) void*)(p))

__device__ __forceinline__ ushort_t f2h(float f) {
    union { _Float16 h; ushort_t u; } v; v.h = (_Float16)f;
    return v.u;
}
__device__ __forceinline__ float h2f(ushort_t u) {
    union { ushort_t u; _Float16 h; } v; v.u = u;
    return (float)v.h;
}

// LDS chunk swizzle (validated R14): slot (row,c) holds logical chunk
// c ^ ((row>>1)&3); store side XORs the GLOBAL chunk, read side XORs the
// read chunk. Both per-thread compile-time constants.

// ---------------- reduce helpers (256-thread blocks) ----------------
__device__ __forceinline__ float blockReduceSumF(float v, float* red, int tid) {
    red[tid] = v; __syncthreads();
    for (int s = 128; s > 0; s >>= 1) {
        if (tid < s) red[tid] += red[tid + s];
        __syncthreads();
    }
    float r = red[0]; __syncthreads();
    return r;
}
__device__ __forceinline__ float blockReduceMaxF(float v, float* red, int tid) {
    red[tid] = v; __syncthreads();
    for (int s = 128; s > 0; s >>= 1) {
        if (tid < s) red[tid] = fmaxf(red[tid], red[tid + s]);
        __syncthreads();
    }
    float r = red[0]; __syncthreads();
    return r;
}

// ---------------- zero a float region (float4/thread) ----------------
__global__ void zero_k(float* __restrict__ p)
{
    int i = blockIdx.x * 256 + threadIdx.x;
    reinterpret_cast<float4*>(p)[i] = make_float4(0.f, 0.f, 0.f, 0.f);
}

// ---------------- weight transpose+cast: wT[n][k] = fp16(w[k][n]) ----------------
__global__ __launch_bounds__(256) void tcast_k(const float* __restrict__ w, ushort_t* __restrict__ wT,
                                               int K, int N)
{
    __shared__ float tb[32][33];
    int tx = threadIdx.x & 31, ty = threadIdx.x >> 5;
    int n0 = blockIdx.x * 32, k0 = blockIdx.y * 32;
#pragma unroll
    for (int i = 0; i < 4; ++i)
        tb[ty + i * 8][tx] = w[(size_t)(k0 + ty + i * 8) * N + n0 + tx];
    __syncthreads();
#pragma unroll
    for (int i = 0; i < 4; ++i)
        wT[(size_t)(n0 + ty + i * 8) * K + k0 + tx] = f2h(tb[tx][ty + i * 8]);
}

// ---------------- batched per-layer weight transpose+cast (qkv 512x1536 + out 512x512) ----
__global__ __launch_bounds__(256) void tcast2_k(const float* __restrict__ w1, ushort_t* __restrict__ wT1,
                                                const float* __restrict__ w2, ushort_t* __restrict__ wT2)
{
    __shared__ float tb[32][33];
    int b = blockIdx.x;
    const float* w; ushort_t* wT; int K, N, n0, k0;
    if (b < 768) { w = w1; wT = wT1; K = 512; N = 1536; n0 = (b % 48) * 32; k0 = (b / 48) * 32; }
    else { b -= 768; w = w2; wT = wT2; K = 512; N = 512; n0 = (b % 16) * 32; k0 = (b / 16) * 32; }
    int tx = threadIdx.x & 31, ty = threadIdx.x >> 5;
#pragma unroll
    for (int i = 0; i < 4; ++i)
        tb[ty + i * 8][tx] = w[(size_t)(k0 + ty + i * 8) * N + n0 + tx];
    __syncthreads();
#pragma unroll
    for (int i = 0; i < 4; ++i)
        wT[(size_t)(n0 + ty + i * 8) * K + k0 + tx] = f2h(tb[tx][ty + i * 8]);
}

// ---------------- cast f32 -> fp16 (4 els/thread) ----------------
__global__ void bcast_k(const float* __restrict__ x, ushort_t* __restrict__ o)
{
    int i = blockIdx.x * 256 + threadIdx.x;
    float4 v = reinterpret_cast<const float4*>(x)[i];
    ushort4 u;
    u.x = f2h(v.x); u.y = f2h(v.y); u.z = f2h(v.z); u.w = f2h(v.w);
    reinterpret_cast<ushort4*>(o)[i] = u;
}

// ---------------- fp16 MFMA GEMM, 128x64 tile (M x N): out = [res +] A@B [+ bias] [relu] ----
__global__ __launch_bounds__(256) void gemm_mn_f16(
    const ushort_t* __restrict__ A, const ushort_t* __restrict__ BT,
    const float* __restrict__ bias, const float* __restrict__ res,
    float* __restrict__ C, ushort_t* __restrict__ Ch,
    int Mvalid, int K, int lda, int ldb, int ldc, int relu, int qscale)
{
    __shared__ ushort_t As[128 * 32];
    __shared__ ushort_t Bs[64 * 32];
    const int tid = threadIdx.x;
    const int wave = tid >> 6, lane = tid & 63;
    const int row0 = blockIdx.y * 128, col0 = blockIdx.x * 64;
    const int wr = wave * 32;
    const int aRow = wave * 16 + (lane >> 2);
    const int aChS = (((lane & 3) ^ ((lane >> 3) & 3)) * 8);
    const int bRow = tid >> 2;
    const int bChS = (((tid & 3) ^ ((tid >> 3) & 3)) * 8);
    const int lr = lane & 15, lq = (lane >> 4) * 4;
    const int lks = (((lane >> 4) ^ ((lr >> 1) & 3)) * 8);
    f32x4 acc[2][4] = {};
    for (int k0 = 0; k0 < K; k0 += 32) {
        __syncthreads();
#pragma unroll
        for (int i = 0; i < 2; ++i) {
            const ushort_t* gp = A + (size_t)(row0 + i * 64 + aRow) * lda + k0 + aChS;
            __builtin_amdgcn_global_load_lds(GPTR(gp), LPTR(As + (i * 64 + wave * 16) * 32), 16, 0, 0);
        }
        const ushort_t* gq = BT + (size_t)(col0 + bRow) * ldb + k0 + bChS;
        __builtin_amdgcn_global_load_lds(GPTR(gq), LPTR(Bs + tid * 8), 16, 0, 0);
        __syncthreads();
        half8 af[2], bfr[4];
#pragma unroll
        for (int mi = 0; mi < 2; ++mi)
            af[mi] = *reinterpret_cast<const half8*>(&As[(wr + mi * 16 + lr) * 32 + lks]);
#pragma unroll
        for (int ni = 0; ni < 4; ++ni)
            bfr[ni] = *reinterpret_cast<const half8*>(&Bs[(ni * 16 + lr) * 32 + lks]);
#pragma unroll
        for (int mi = 0; mi < 2; ++mi)
#pragma unroll
            for (int ni = 0; ni < 4; ++ni)
                acc[mi][ni] = __builtin_amdgcn_mfma_f32_16x16x32_f16(af[mi], bfr[ni], acc[mi][ni], 0, 0, 0);
    }
#pragma unroll
    for (int mi = 0; mi < 2; ++mi) {
#pragma unroll
        for (int q = 0; q < 4; ++q) {
            int r = row0 + wr + mi * 16 + lq + q;
            if (r >= Mvalid) continue;
#pragma unroll
            for (int ni = 0; ni < 4; ++ni) {
                int c = col0 + ni * 16 + lr;
                float v = acc[mi][ni][q];
                if (bias) v += bias[c];
                if (res)  v += res[(size_t)r * ldc + c];
                if (relu) v = fmaxf(v, 0.f);
                if (Ch) {
                    if (qscale && c < 512) v *= SCALE;
                    Ch[(size_t)r * ldc + c] = f2h(v);
                } else {
                    C[(size_t)r * ldc + c] = v;
                }
            }
        }
    }
}

// ---------------- batched fp16 MFMA 256^3, 64x64 tiles: C = diag*I + ss*(A@B) ----------------
__global__ __launch_bounds__(256) void bgemm64_f16(
    const ushort_t* __restrict__ A, const ushort_t* __restrict__ B,
    ushort_t* __restrict__ C, float diag, float ss,
    ushort_t* __restrict__ C2, float diag2, float ss2)
{
    __shared__ ushort_t As[64 * 32];
    __shared__ ushort_t Bs[64 * 32];
    const int h = blockIdx.z;
    const ushort_t* Ah = A + (size_t)h * 65536;
    const ushort_t* Bh = B + (size_t)h * 65536;
    const int tid = threadIdx.x;
    const int wave = tid >> 6, lane = tid & 63;
    const int row0 = blockIdx.y * 64, col0 = blockIdx.x * 64;
    const int wr = (wave >> 1) * 32, wc = (wave & 1) * 32;
    const int aRow = tid >> 2;
    const int aChS = (((tid & 3) ^ ((tid >> 3) & 3)) * 8);
    const int kp = (tid >> 3) & 15, nc = tid & 7;
    const int kk = (kp * 2) ^ ((nc & 3) << 3);
    const int lr = lane & 15, lk = (lane >> 4) * 8, lq = (lane >> 4) * 4;
    const int lks = (((lane >> 4) ^ ((lr >> 1) & 3)) * 8);
    f32x4 acc[2][2] = {};
    for (int k0 = 0; k0 < 256; k0 += 32) {
        __syncthreads();
        const ushort_t* gp = Ah + (size_t)(row0 + aRow) * 256 + k0 + aChS;
        __builtin_amdgcn_global_load_lds(GPTR(gp), LPTR(As + tid * 8), 16, 0, 0);
        if (tid < 128) {
            const ushort_t* bp = Bh + (size_t)(k0 + kp * 2) * 256 + col0 + nc * 8;
            short8 v0 = *reinterpret_cast<const short8*>(bp);
            short8 v1 = *reinterpret_cast<const short8*>(bp + 256);
#pragma unroll
            for (int j = 0; j < 8; ++j) {
                unsigned int pk = ((unsigned int)(ushort_t)v1[j] << 16) | (unsigned int)(ushort_t)v0[j];
                *reinterpret_cast<unsigned int*>(&Bs[(nc * 8 + j) * 32 + kk]) = pk;
            }
        }
        __syncthreads();
        half8 af[2], bfr[2];
#pragma unroll
        for (int mi = 0; mi < 2; ++mi)
            af[mi] = *reinterpret_cast<const half8*>(&As[(wr + mi * 16 + lr) * 32 + lks]);
#pragma unroll
        for (int ni = 0; ni < 2; ++ni) {
            int nn = wc + ni * 16 + lr;
            bfr[ni] = *reinterpret_cast<const half8*>(&Bs[nn * 32 + (lk ^ (((nn >> 3) & 3) << 3))]);
        }
#pragma unroll
        for (int mi = 0; mi < 2; ++mi)
#pragma unroll
            for (int ni = 0; ni < 2; ++ni)
                acc[mi][ni] = __builtin_amdgcn_mfma_f32_16x16x32_f16(af[mi], bfr[ni], acc[mi][ni], 0, 0, 0);
    }
    ushort_t* Chp = C + (size_t)h * 65536;
#pragma unroll
    for (int mi = 0; mi < 2; ++mi)
#pragma unroll
        for (int ni = 0; ni < 2; ++ni)
#pragma unroll
            for (int q = 0; q < 4; ++q) {
                int r = row0 + wr + mi * 16 + lq + q;
                int c = col0 + wc + ni * 16 + lr;
                float v = ss * acc[mi][ni][q];
                if (r == c) v += diag;
                Chp[(size_t)r * 256 + c] = f2h(v);
                if (C2) {
                    float v2 = ss2 * acc[mi][ni][q];
                    if (r == c) v2 += diag2;
                    C2[(size_t)h * 65536 + (size_t)r * 256 + c] = f2h(v2);
                }
            }
}

// ---------------- fused S3/PV flash kernel ----------------
__global__ __launch_bounds__(256) void fs3_k(
    const ushort_t* __restrict__ ql, const ushort_t* __restrict__ qkv16,
    float* __restrict__ part, float* __restrict__ rsum)
{
    __shared__ ushort_t Qs[2][128 * 32];
    __shared__ ushort_t Bs[64 * 32];
    __shared__ ushort_t Pl[128][72];
    const int ks = blockIdx.x, row0 = blockIdx.y * 128, h = blockIdx.z;
    const ushort_t* Ah = ql + (size_t)h * 16384;
    const ushort_t* Kh = qkv16 + 512 + h * 64;
    const ushort_t* Vh = qkv16 + 1024 + h * 64;
    const int tid = threadIdx.x;
    const int wave = tid >> 6, lane = tid & 63;
    const int wr = wave * 32;
    const int aRow = wave * 16 + (lane >> 2);
    const int aChS = (((lane & 3) ^ ((lane >> 3) & 3)) * 8);
    const int bRow = tid >> 2;
    const int bChS = (((tid & 3) ^ ((tid >> 3) & 3)) * 8);
    const int lr = lane & 15, lk = (lane >> 4) * 8, lq = (lane >> 4) * 4;
    const int lks = (((lane >> 4) ^ ((lr >> 1) & 3)) * 8);
    const int kp = (tid >> 3) & 15, nc = tid & 7;
    const int kk = (kp * 2) ^ ((nc & 3) << 3);
#pragma unroll
    for (int hh = 0; hh < 2; ++hh)
#pragma unroll
        for (int i = 0; i < 2; ++i) {
            const ushort_t* gp = Ah + (size_t)(row0 + i * 64 + aRow) * 64 + hh * 32 + aChS;
            __builtin_amdgcn_global_load_lds(GPTR(gp), LPTR(Qs[hh] + (i * 64 + wave * 16) * 32), 16, 0, 0);
        }
    f32x4 aco[2][4] = {};
    float rs[2][4] = {};
    for (int c = 0; c < KC3; c += 64) {
        const int tok0 = ks * KC3 + c;
        f32x4 acs[2][4] = {};
#pragma unroll
        for (int k0 = 0; k0 < 64; k0 += 32) {
            __syncthreads();
            const ushort_t* gq = Kh + (size_t)(tok0 + bRow) * 1536 + k0 + bChS;
            __builtin_amdgcn_global_load_lds(GPTR(gq), LPTR(Bs + tid * 8), 16, 0, 0);
            __syncthreads();
            half8 af[2], bfr[4];
#pragma unroll
            for (int mi = 0; mi < 2; ++mi)
                af[mi] = *reinterpret_cast<const half8*>(&Qs[k0 >> 5][(wr + mi * 16 + lr) * 32 + lks]);
#pragma unroll
            for (int ni = 0; ni < 4; ++ni)
                bfr[ni] = *reinterpret_cast<const half8*>(&Bs[(ni * 16 + lr) * 32 + lks]);
#pragma unroll
            for (int mi = 0; mi < 2; ++mi)
#pragma unroll
                for (int ni = 0; ni < 4; ++ni)
                    acs[mi][ni] = __builtin_amdgcn_mfma_f32_16x16x32_f16(af[mi], bfr[ni], acs[mi][ni], 0, 0, 0);
        }
#pragma unroll
        for (int mi = 0; mi < 2; ++mi)
#pragma unroll
            for (int q = 0; q < 4; ++q) {
                int r = wr + mi * 16 + lq + q;
                float s = 0.f;
#pragma unroll
                for (int ni = 0; ni < 4; ++ni) {
                    float e = __expf(acs[mi][ni][q]);
                    Pl[r][ni * 16 + lr] = f2h(e);
                    s += e;
                }
                for (int off = 8; off; off >>= 1) s += __shfl_xor(s, off, 64);
                rs[mi][q] += s;
            }
#pragma unroll
        for (int k0 = 0; k0 < 64; k0 += 32) {
            __syncthreads();
            if (tid < 128) {
                const ushort_t* bp = Vh + (size_t)(tok0 + k0 + kp * 2) * 1536 + nc * 8;
                short8 v0 = *reinterpret_cast<const short8*>(bp);
                short8 v1 = *reinterpret_cast<const short8*>(bp + 1536);
#pragma unroll
                for (int j = 0; j < 8; ++j) {
                    unsigned int pk = ((unsigned int)(ushort_t)v1[j] << 16) | (unsigned int)(ushort_t)v0[j];
                    *reinterpret_cast<unsigned int*>(&Bs[(nc * 8 + j) * 32 + kk]) = pk;
                }
            }
            __syncthreads();
            half8 af[2], bfr[4];
#pragma unroll
            for (int mi = 0; mi < 2; ++mi)
                af[mi] = *reinterpret_cast<const half8*>(&Pl[wr + mi * 16 + lr][k0 + lk]);
#pragma unroll
            for (int ni = 0; ni < 4; ++ni) {
                int nn = ni * 16 + lr;
                bfr[ni] = *reinterpret_cast<const half8*>(&Bs[nn * 32 + (lk ^ (((nn >> 3) & 3) << 3))]);
            }
#pragma unroll
            for (int mi = 0; mi < 2; ++mi)
#pragma unroll
                for (int ni = 0; ni < 4; ++ni)
                    aco[mi][ni] = __builtin_amdgcn_mfma_f32_16x16x32_f16(af[mi], bfr[ni], aco[mi][ni], 0, 0, 0);
        }
    }
    float* pp = part + (size_t)(ks * 8 + h) * 16384;
#pragma unroll
    for (int mi = 0; mi < 2; ++mi)
#pragma unroll
        for (int q = 0; q < 4; ++q) {
            int r = row0 + wr + mi * 16 + lq + q;
#pragma unroll
            for (int ni = 0; ni < 4; ++ni)
                pp[(size_t)r * 64 + ni * 16 + lr] = aco[mi][ni][q];
            if (lr == 0) atomicAdd(&rsum[h * 256 + r], rs[mi][q]);
        }
}

__global__ __launch_bounds__(256) void pv_reduce_k(const float* __restrict__ part,
                                                   const float* __restrict__ rsum,
                                                   ushort_t* __restrict__ av)
{
    int idx = blockIdx.x * 256 + threadIdx.x;   // 131072
    int rc = idx >> 6;
    float s = 0.f;
#pragma unroll
    for (int ks = 0; ks < KS3; ++ks)
        s += part[(size_t)ks * 131072 + idx];
    av[idx] = f2h(s / rsum[rc]);
}

// ---------------- fused a1 path: attn = softmax(q @ kl^T) @ W ----------------
__global__ __launch_bounds__(256) void fa1_k(
    const ushort_t* __restrict__ qkv16, const ushort_t* __restrict__ kl,
    const ushort_t* __restrict__ W, ushort_t* __restrict__ attn)
{
    __shared__ ushort_t Pl[128][264];
    __shared__ ushort_t As[128 * 32];
    __shared__ ushort_t Bs[64 * 32];
    __shared__ float rs_l[128];
    const int h = blockIdx.y;
    const int row0 = blockIdx.x * 128;
    const ushort_t* Aq = qkv16 + h * 64;
    const ushort_t* klh = kl + (size_t)h * 16384;
    const ushort_t* Wh = W + (size_t)h * 16384;
    const int tid = threadIdx.x;
    const int wave = tid >> 6, lane = tid & 63;
    const int wr = wave * 32;
    const int aRow = wave * 16 + (lane >> 2);
    const int aChS = (((lane & 3) ^ ((lane >> 3) & 3)) * 8);
    const int bRow = tid >> 2;
    const int bChS = (((tid & 3) ^ ((tid >> 3) & 3)) * 8);
    const int lr = lane & 15, lk = (lane >> 4) * 8, lq = (lane >> 4) * 4;
    const int lks = (((lane >> 4) ^ ((lr >> 1) & 3)) * 8);
    const int kp = (tid >> 3) & 15, ncs = tid & 7;
    const int kk = (kp * 2) ^ ((ncs & 3) << 3);
    float rs[2][4] = {};
    for (int nc0 = 0; nc0 < 256; nc0 += 64) {
        f32x4 acc[2][4] = {};
        for (int k0 = 0; k0 < 64; k0 += 32) {
            __syncthreads();
#pragma unroll
            for (int i = 0; i < 2; ++i) {
                const ushort_t* gp = Aq + (size_t)(row0 + i * 64 + aRow) * 1536 + k0 + aChS;
                __builtin_amdgcn_global_load_lds(GPTR(gp), LPTR(As + (i * 64 + wave * 16) * 32), 16, 0, 0);
            }
            const ushort_t* gq = klh + (size_t)(nc0 + bRow) * 64 + k0 + bChS;
            __builtin_amdgcn_global_load_lds(GPTR(gq), LPTR(Bs + tid * 8), 16, 0, 0);
            __syncthreads();
            half8 af[2], bfr[4];
#pragma unroll
            for (int mi = 0; mi < 2; ++mi)
                af[mi] = *reinterpret_cast<const half8*>(&As[(wr + mi * 16 + lr) * 32 + lks]);
#pragma unroll
            for (int ni = 0; ni < 4; ++ni)
                bfr[ni] = *reinterpret_cast<const half8*>(&Bs[(ni * 16 + lr) * 32 + lks]);
#pragma unroll
            for (int mi = 0; mi < 2; ++mi)
#pragma unroll
                for (int ni = 0; ni < 4; ++ni)
                    acc[mi][ni] = __builtin_amdgcn_mfma_f32_16x16x32_f16(af[mi], bfr[ni], acc[mi][ni], 0, 0, 0);
        }
#pragma unroll
        for (int mi = 0; mi < 2; ++mi)
#pragma unroll
            for (int q = 0; q < 4; ++q) {
                int r = wr + mi * 16 + lq + q;
                float s = 0.f;
#pragma unroll
                for (int ni = 0; ni < 4; ++ni) {
                    float e = __expf(acc[mi][ni][q]);
                    Pl[r][nc0 + ni * 16 + lr] = f2h(e);
                    s += e;
                }
                for (int off = 8; off; off >>= 1) s += __shfl_xor(s, off, 64);
                rs[mi][q] += s;
            }
    }
    if (lr == 0) {
#pragma unroll
        for (int mi = 0; mi < 2; ++mi)
#pragma unroll
            for (int q = 0; q < 4; ++q)
                rs_l[wr + mi * 16 + lq + q] = rs[mi][q];
    }
    __syncthreads();
    f32x4 acc[2][4] = {};
    for (int k0 = 0; k0 < 256; k0 += 32) {
        __syncthreads();
        if (tid < 128) {
            const ushort_t* bp = Wh + (size_t)(k0 + kp * 2) * 64 + ncs * 8;
            short8 v0 = *reinterpret_cast<const short8*>(bp);
            short8 v1 = *reinterpret_cast<const short8*>(bp + 64);
#pragma unroll
            for (int j = 0; j < 8; ++j) {
                unsigned int pk = ((unsigned int)(ushort_t)v1[j] << 16) | (unsigned int)(ushort_t)v0[j];
                *reinterpret_cast<unsigned int*>(&Bs[(ncs * 8 + j) * 32 + kk]) = pk;
            }
        }
        __syncthreads();
        half8 af[2], bfr[4];
#pragma unroll
        for (int mi = 0; mi < 2; ++mi)
            af[mi] = *reinterpret_cast<const half8*>(&Pl[wr + mi * 16 + lr][k0 + lk]);
#pragma unroll
        for (int ni = 0; ni < 4; ++ni) {
            int nn = ni * 16 + lr;
            bfr[ni] = *reinterpret_cast<const half8*>(&Bs[nn * 32 + (lk ^ (((nn >> 3) & 3) << 3))]);
        }
#pragma unroll
        for (int mi = 0; mi < 2; ++mi)
#pragma unroll
            for (int ni = 0; ni < 4; ++ni)
                acc[mi][ni] = __builtin_amdgcn_mfma_f32_16x16x32_f16(af[mi], bfr[ni], acc[mi][ni], 0, 0, 0);
    }
#pragma unroll
    for (int mi = 0; mi < 2; ++mi)
#pragma unroll
        for (int q = 0; q < 4; ++q) {
            int rloc = wr + mi * 16 + lq + q;
            int t = row0 + rloc;
            float inv = 1.f / rs_l[rloc];
#pragma unroll
            for (int ni = 0; ni < 4; ++ni)
                attn[(size_t)t * 512 + h * 64 + ni * 16 + lr] = f2h(acc[mi][ni][q] * inv);
        }
}

// ---------------- W = z @ av (per head 256x256 @ 256x64), fp16, 4 rows/block ----------------
__global__ __launch_bounds__(256) void wmat_k(const ushort_t* __restrict__ z,
                                              const ushort_t* __restrict__ av,
                                              ushort_t* __restrict__ W)
{
    int idx = blockIdx.x * 4 + (threadIdx.x >> 6);
    int h = idx >> 8, m = idx & 255, d = threadIdx.x & 63;
    const ushort_t* zp = z + (size_t)h * 65536 + (size_t)m * 256;
    const ushort_t* ap = av + (size_t)h * 16384 + d;
    float acc = 0.f;
    for (int j = 0; j < 256; ++j) acc += h2f(zp[j]) * h2f(ap[(size_t)j * 64]);
    W[((size_t)h * 256 + m) * 64 + d] = f2h(acc);
}

// ---------------- fixup: cls token + wrap rows ----------------
__global__ void fixup_k(const float* __restrict__ cls, float* __restrict__ h)
{
    int i = blockIdx.x * 256 + threadIdx.x;
    if (i < 512) {
        h[i] = cls[i];
    } else {
        int j = i - 512;
        h[(size_t)8193 * 512 + j] = h[512 + j];
    }
}

// ---------------- layernorm + front zero-pad: out[NP][512] fp16 ----------------
__global__ __launch_bounds__(256) void ln_pad_k(
    const float* __restrict__ h, const float* __restrict__ g, const float* __restrict__ b,
    ushort_t* __restrict__ out)
{
    int row = blockIdx.x, tid = threadIdx.x;
    __shared__ float red[256];
    ushort_t* o = out + (size_t)row * 512;
    if (row < PAD) { o[tid] = 0; o[tid + 256] = 0; return; }
    const float* x = h + (size_t)(row - PAD) * 512;
    float v0 = x[tid], v1 = x[tid + 256];
    float mu = blockReduceSumF(v0 + v1, red, tid) * (1.f / 512.f);
    float d0 = v0 - mu, d1 = v1 - mu;
    float var = blockReduceSumF(d0 * d0 + d1 * d1, red, tid) * (1.f / 512.f);
    float rstd = rsqrtf(var + 1e-5f);
    o[tid]       = f2h(d0 * rstd * g[tid] + b[tid]);
    o[tid + 256] = f2h(d1 * rstd * g[tid + 256] + b[tid + 256]);
}

// ---------------- landmark means (q already pre-scaled), 4 (h,m) pairs/block ----------------
__global__ __launch_bounds__(256) void landmark_k(const ushort_t* __restrict__ qkv,
                                                  ushort_t* __restrict__ ql,
                                                  ushort_t* __restrict__ kl)
{
    int idx = blockIdx.x * 4 + (threadIdx.x >> 6);
    int h = idx >> 8, m = idx & 255, d = threadIdx.x & 63;
    const ushort_t* base = qkv + (size_t)(m * LCH) * 1536 + h * 64 + d;
    float sq = 0.f, sk = 0.f;
    for (int i = 0; i < LCH; ++i) {
        sq += h2f(base[(size_t)i * 1536]);
        sk += h2f(base[(size_t)i * 1536 + 512]);
    }
    ql[((size_t)h * 256 + m) * 64 + d] = f2h(sq * (1.f / (float)LCH));
    kl[((size_t)h * 256 + m) * 64 + d] = f2h(sk * (1.f / (float)LCH));
}

// ---------------- a2 = softmax(ql @ kl^T), fp16 out, fused colsum atomics ----------------
__global__ __launch_bounds__(256) void a2_k(
    const ushort_t* __restrict__ ql, const ushort_t* __restrict__ kl, ushort_t* __restrict__ a2,
    float* __restrict__ cs)
{
    int h = blockIdx.x >> 8, r = blockIdx.x & 255, tid = threadIdx.x;
    __shared__ float qv[64]; __shared__ float red[256];
    if (tid < 64) qv[tid] = h2f(ql[((size_t)h * 256 + r) * 64 + tid]);
    __syncthreads();
    const ushort_t* kp = kl + ((size_t)h * 256 + tid) * 64;
    float dot = 0.f;
#pragma unroll
    for (int d = 0; d < 64; ++d) dot += qv[d] * h2f(kp[d]);
    float mx = blockReduceMaxF(dot, red, tid);
    float e = expf(dot - mx);
    float s = blockReduceSumF(e, red, tid);
    float v = e / s;
    a2[((size_t)h * 256 + r) * 256 + tid] = f2h(v);
    atomicAdd(&cs[h * 256 + tid], v);
}

// ---------------- zinit: scal computed locally from cs; z = a2^T * scal ----------------
__global__ __launch_bounds__(256) void zinit_k(const ushort_t* __restrict__ a2,
                                               const float* __restrict__ cs,
                                               ushort_t* __restrict__ z)
{
    __shared__ float red[256];
    int h = blockIdx.x >> 8, r = blockIdx.x & 255, c = threadIdx.x;
    float m2 = -1e30f;
    for (int i = c; i < 2048; i += 256) m2 = fmaxf(m2, cs[i]);
    m2 = blockReduceMaxF(m2, red, c);
    float scal = 1.f / m2;
    z[(size_t)h * 65536 + (size_t)r * 256 + c] =
        f2h(h2f(a2[(size_t)h * 65536 + (size_t)c * 256 + r]) * scal);
}

// ---------------- tiled depthwise 33-tap conv over tokens on v (fp16), added to fp16 attn ----------------
#define CTT 64
__global__ __launch_bounds__(256) void conv2_k(const ushort_t* __restrict__ qkv,
                                               const float* __restrict__ cw,
                                               ushort_t* __restrict__ attn)
{
    __shared__ float vt[CTT + 32][64];
    int t0 = blockIdx.x * CTT;
    int h = blockIdx.y;
    int tid = threadIdx.x;
    for (int s = tid; s < (CTT + 32) * 8; s += 256) {
        int row = s >> 3, q8 = s & 7;
        int tt = t0 - 16 + row;
        if (tt >= 0 && tt < NP) {
            short8 v = *reinterpret_cast<const short8*>(qkv + (size_t)tt * 1536 + 1024 + h * 64 + q8 * 8);
#pragma unroll
            for (int j = 0; j < 8; ++j) vt[row][q8 * 8 + j] = h2f((ushort_t)v[j]);
        } else {
#pragma unroll
            for (int j = 0; j < 8; ++j) vt[row][q8 * 8 + j] = 0.f;
        }
    }
    float w33[33];
#pragma unroll
    for (int j = 0; j < 33; ++j) w33[j] = cw[h * 33 + j];
    __syncthreads();
    int c = tid & 63, tr = tid >> 6;
    float win[48];
#pragma unroll
    for (int j = 0; j < 48; ++j) win[j] = vt[tr * 16 + j][c];
#pragma unroll
    for (int i = 0; i < 16; ++i) {
        float acc = 0.f;
#pragma unroll
        for (int j = 0; j < 33; ++j) acc += w33[j] * win[i + j];
        size_t idx = (size_t)(t0 + tr * 16 + i) * 512 + h * 64 + c;
        attn[idx] = f2h(h2f(attn[idx]) + acc);
    }
}

// ---------------- PPEG tiled: transposed f32 LDS [tok][ch], PCG=8, float4 reads ----------------
#define PTS  16
#define PIT  22
#define PITT (PIT*PIT)   // 484
#define PCG  8
#define PSTR 12
__global__ __launch_bounds__(256) void ppeg_tiled_k(
    const float* __restrict__ hin,
    const float* __restrict__ w7, const float* __restrict__ b7,
    const float* __restrict__ w5, const float* __restrict__ b5,
    const float* __restrict__ w3, const float* __restrict__ b3,
    float* __restrict__ hout)
{
    __shared__ float inb[PITT][PSTR];
    __shared__ float wcT[49][PCG];
    __shared__ float bs[PCG];
    int tid = threadIdx.x;
    int c0 = blockIdx.z * PCG;
    int ty0 = blockIdx.y * PTS, tx0 = blockIdx.x * PTS;
    if (blockIdx.x == 0 && blockIdx.y == 0 && tid < PCG)
        hout[c0 + tid] = hin[c0 + tid];
    for (int idx = tid; idx < PITT * 2; idx += 256) {
        int tok = idx >> 1, q = idx & 1;
        int gy = ty0 - 3 + tok / PIT, gx = tx0 - 3 + tok % PIT;
        float4 v = make_float4(0.f, 0.f, 0.f, 0.f);
        if (gy >= 0 && gy < HS && gx >= 0 && gx < HS)
            v = *reinterpret_cast<const float4*>(hin + (size_t)(1 + gy * HS + gx) * 512 + c0 + q * 4);
        *reinterpret_cast<float4*>(&inb[tok][q * 4]) = v;
    }
    for (int idx = tid; idx < PCG * 49; idx += 256) {
        int c = idx / 49, t = idx % 49;
        int ky = t / 7, kx = t % 7, dy = ky - 3, dx = kx - 3;
        float w = w7[(size_t)(c0 + c) * 49 + t];
        if (dy >= -2 && dy <= 2 && dx >= -2 && dx <= 2)
            w += w5[(size_t)(c0 + c) * 25 + (dy + 2) * 5 + (dx + 2)];
        if (dy >= -1 && dy <= 1 && dx >= -1 && dx <= 1)
            w += w3[(size_t)(c0 + c) * 9 + (dy + 1) * 3 + (dx + 1)];
        wcT[t][c] = w;
    }
    if (tid < PCG) bs[tid] = b7[c0 + tid] + b5[c0 + tid] + b3[c0 + tid];
    __syncthreads();
    int oy = tid >> 4, ox = tid & 15;
    int gy = ty0 + oy, gx = tx0 + ox;
    if (gy >= HS || gx >= HS) return;
    float acc[PCG];
    {
        const float* cp = &inb[(oy + 3) * PIT + ox + 3][0];
        float4 i0 = *reinterpret_cast<const float4*>(cp);
        float4 i1 = *reinterpret_cast<const float4*>(cp + 4);
        acc[0] = i0.x + bs[0]; acc[1] = i0.y + bs[1]; acc[2] = i0.z + bs[2]; acc[3] = i0.w + bs[3];
        acc[4] = i1.x + bs[4]; acc[5] = i1.y + bs[5]; acc[6] = i1.z + bs[6]; acc[7] = i1.w + bs[7];
    }
#pragma unroll
    for (int ky = 0; ky < 7; ++ky)
#pragma unroll
        for (int kx = 0; kx < 7; ++kx) {
            int t = ky * 7 + kx;
            const float* dp = &inb[(oy + ky) * PIT + ox + kx][0];
            float4 d0 = *reinterpret_cast<const float4*>(dp);
            float4 d1 = *reinterpret_cast<const float4*>(dp + 4);
            float4 w0 = *reinterpret_cast<const float4*>(&wcT[t][0]);
            float4 w1 = *reinterpret_cast<const float4*>(&wcT[t][4]);
            acc[0] += w0.x * d0.x; acc[1] += w0.y * d0.y;
            acc[2] += w0.z * d0.z; acc[3] += w0.w * d0.w;
            acc[4] += w1.x * d1.x; acc[5] += w1.y * d1.y;
            acc[6] += w1.z * d1.z; acc[7] += w1.w * d1.w;
        }
    float* out = hout + (size_t)(1 + gy * HS + gx) * 512 + c0;
    *reinterpret_cast<float4*>(out)     = make_float4(acc[0], acc[1], acc[2], acc[3]);
    *reinterpret_cast<float4*>(out + 4) = make_float4(acc[4], acc[5], acc[6], acc[7]);
}

// ---------------- final LN(row0) + fc2 + softmax + argmax ----------------
__global__ __launch_bounds__(256) void final_k(const float* __restrict__ h,
                                               const float* __restrict__ g, const float* __restrict__ bb,
                                               const float* __restrict__ w, const float* __restrict__ fb,
                                               float* __restrict__ out)
{
    __shared__ float red[256];
    int tid = threadIdx.x;
    float v0 = h[tid], v1 = h[tid + 256];
    float mu = blockReduceSumF(v0 + v1, red, tid) * (1.f / 512.f);
    float d0 = v0 - mu, d1 = v1 - mu;
    float var = blockReduceSumF(d0 * d0 + d1 * d1, red, tid) * (1.f / 512.f);
    float rstd = rsqrtf(var + 1e-5f);
    float e0 = d0 * rstd * g[tid] + bb[tid];
    float e1 = d1 * rstd * g[tid + 256] + bb[tid + 256];
    out[5 + tid] = e0;
    out[5 + 256 + tid] = e1;
    float l0p = e0 * w[tid * 2] + e1 * w[(tid + 256) * 2];
    float l1p = e0 * w[tid * 2 + 1] + e1 * w[(tid + 256) * 2 + 1];
    float l0 = blockReduceSumF(l0p, red, tid);
    float l1 = blockReduceSumF(l1p, red, tid);
    if (!tid) {
        l0 += fb[0]; l1 += fb[1];
        out[0] = l0; out[1] = l1;
        float mx = fmaxf(l0, l1);
        float p0 = expf(l0 - mx), p1 = expf(l1 - mx);
        float si = 1.f / (p0 + p1);
        out[2] = p0 * si; out[3] = p1 * si;
        out[4] = (l1 > l0) ? 1.f : 0.f;
    }
}

// ---------------- host orchestration ----------------
struct WsPtrs {
    float *h, *h2, *cs, *rsum3, *part;
    ushort_t *xbB, *qkv16, *ql16, *kl16, *a2h, *zh, *z2h, *xzh, *t1h, *t2h;
    ushort_t *av16, *W16, *qkvT, *outT, *x16, *fc1T, *S16;
};

static void run_attn(float* hbuf, const float* ln_g, const float* ln_b,
                     const float* qkv_w, const float* out_w, const float* out_b,
                     const float* conv_w, const WsPtrs& P, hipStream_t s)
{
    tcast2_k<<<1024, 256, 0, s>>>(qkv_w, P.qkvT, out_w, P.outT);
    ln_pad_k<<<NP, 256, 0, s>>>(hbuf, ln_g, ln_b, P.xbB);
    gemm_mn_f16<<<dim3(1536 / 64, NP / 128), 256, 0, s>>>(P.xbB, P.qkvT, nullptr, nullptr,
                                                          nullptr, P.qkv16, NP, 512, 512, 512, 1536, 0, 1);
    landmark_k<<<512, 256, 0, s>>>(P.qkv16, P.ql16, P.kl16);
    // zero cs (2048) + rsum3 (2048) = 4096 floats contiguous
    zero_k<<<4, 256, 0, s>>>(P.cs);
    a2_k<<<2048, 256, 0, s>>>(P.ql16, P.kl16, P.a2h, P.cs);
    zinit_k<<<2048, 256, 0, s>>>(P.a2h, P.cs, P.zh);
    ushort_t* za = P.zh; ushort_t* zb = P.z2h;
    for (int it = 0; it < 6; ++it) {
        bgemm64_f16<<<dim3(4, 4, 8), 256, 0, s>>>(P.a2h, za, P.xzh, 0.f, 1.f, P.t1h, 7.f, -1.f);
        bgemm64_f16<<<dim3(4, 4, 8), 256, 0, s>>>(P.xzh, P.t1h, P.t2h, 15.f, -1.f, nullptr, 0.f, 0.f);
        bgemm64_f16<<<dim3(4, 4, 8), 256, 0, s>>>(P.xzh, P.t2h, P.t1h, 13.f, -1.f, nullptr, 0.f, 0.f);
        bgemm64_f16<<<dim3(4, 4, 8), 256, 0, s>>>(za, P.t1h, zb, 0.f, 0.25f, nullptr, 0.f, 0.f);
        ushort_t* tmp = za; za = zb; zb = tmp;
    }
    // av path: fused flash S3/PV -> reduce
    fs3_k<<<dim3(KS3, 2, 8), 256, 0, s>>>(P.ql16, P.qkv16, P.part, P.rsum3);
    pv_reduce_k<<<512, 256, 0, s>>>(P.part, P.rsum3, P.av16);
    wmat_k<<<512, 256, 0, s>>>(za, P.av16, P.W16);
    // a1 path: fully fused
    fa1_k<<<dim3(NP / 128, 8), 256, 0, s>>>(P.qkv16, P.kl16, P.W16, P.xbB);
    conv2_k<<<dim3(NP / CTT, 8), 256, 0, s>>>(P.qkv16, conv_w, P.xbB);
    gemm_mn_f16<<<dim3(512 / 64, (N1 + 127) / 128), 256, 0, s>>>(P.xbB + (size_t)PAD * 512, P.outT,
                                                                 out_b, hbuf, hbuf, nullptr,
                                                                 N1, 512, 512, 512, 512, 0, 0);
}

extern "C" void kernel_launch(void* const* d_in, const int* in_sizes, int n_in,
                              void* d_out, int out_size, void* d_ws, size_t ws_size,
                              hipStream_t stream)
{
    (void)in_sizes; (void)n_in; (void)out_size; (void)ws_size;
    const float* x       = (const float*)d_in[0];
    const float* fc1_w   = (const float*)d_in[1];
    const float* fc1_b   = (const float*)d_in[2];
    const float* cls_tok = (const float*)d_in[3];
    const float* ln1_g   = (const float*)d_in[4];
    const float* ln1_b   = (const float*)d_in[5];
    const float* qkv1_w  = (const float*)d_in[6];
    const float* out1_w  = (const float*)d_in[7];
    const float* out1_b  = (const float*)d_in[8];
    const float* conv1_w = (const float*)d_in[9];
    const float* ln2_g   = (const float*)d_in[10];
    const float* ln2_b   = (const float*)d_in[11];
    const float* qkv2_w  = (const float*)d_in[12];
    const float* out2_w  = (const float*)d_in[13];
    const float* out2_b  = (const float*)d_in[14];
    const float* conv2_w = (const float*)d_in[15];
    const float* pg7_w   = (const float*)d_in[16];
    const float* pg7_b   = (const float*)d_in[17];
    const float* pg5_w   = (const float*)d_in[18];
    const float* pg5_b   = (const float*)d_in[19];
    const float* pg3_w   = (const float*)d_in[20];
    const float* pg3_b   = (const float*)d_in[21];
    const float* norm_g  = (const float*)d_in[22];
    const float* norm_b  = (const float*)d_in[23];
    const float* fc2_w   = (const float*)d_in[24];
    const float* fc2_b   = (const float*)d_in[25];

    float* ws = (float*)d_ws;
    WsPtrs P;
    float* cur = ws;
    P.h     = cur; cur += (size_t)N1 * 512;
    P.h2    = cur; cur += (size_t)N1 * 512;
    P.xbB   = (ushort_t*)cur; cur += (size_t)NP * 512 / 2;
    P.qkv16 = (ushort_t*)cur; cur += (size_t)NP * 1536 / 2;
    P.ql16  = (ushort_t*)cur; cur += 65536;
    P.kl16  = (ushort_t*)cur; cur += 65536;
    P.a2h   = (ushort_t*)cur; cur += 262144;
    P.zh    = (ushort_t*)cur; cur += 262144;
    P.z2h   = (ushort_t*)cur; cur += 262144;
    P.xzh   = (ushort_t*)cur; cur += 262144;
    P.t1h   = (ushort_t*)cur; cur += 262144;
    P.t2h   = (ushort_t*)cur; cur += 262144;
    P.av16  = (ushort_t*)cur; cur += 65536;
    P.W16   = (ushort_t*)cur; cur += 65536;
    P.cs    = cur; cur += 2048;                     // contiguous with rsum3 (zeroed together)
    P.rsum3 = cur; cur += 2048;
    P.qkvT  = (ushort_t*)cur; cur += 393216 + 64;   // 1536x512 halfs
    P.outT  = (ushort_t*)cur; cur += 131072 + 64;   // 512x512 halfs
    P.part  = cur; cur += (size_t)KS3 * 131072;
    P.S16   = (ushort_t*)cur; cur += (size_t)NTOK * INDIM / 2 + (size_t)512 * 1024 / 2 + 64;
    P.x16   = P.S16;                                         // 8192x1024 halfs (prep only)
    P.fc1T  = P.S16 + (size_t)NTOK * INDIM;                  // 512x1024 halfs

    bcast_k<<<(NTOK * INDIM) / 1024, 256, 0, stream>>>(x, P.x16);
    tcast_k<<<dim3(512 / 32, 1024 / 32), 256, 0, stream>>>(fc1_w, P.fc1T, 1024, 512);
    gemm_mn_f16<<<dim3(512 / 64, NTOK / 128), 256, 0, stream>>>(P.x16, P.fc1T, fc1_b, nullptr,
                                                                P.h + 512, nullptr,
                                                                NTOK, 1024, 1024, 1024, 512, 1, 0);
    fixup_k<<<180, 256, 0, stream>>>(cls_tok, P.h);
    run_attn(P.h, ln1_g, ln1_b, qkv1_w, out1_w, out1_b, conv1_w, P, stream);
    ppeg_tiled_k<<<dim3(6, 6, 512 / PCG), 256, 0, stream>>>(P.h, pg7_w, pg7_b, pg5_w, pg5_b,
                                                            pg3_w, pg3_b, P.h2);
    run_attn(P.h2, ln2_g, ln2_b, qkv2_w, out2_w, out2_b, conv2_w, P, stream);
    final_k<<<1, 256, 0, stream>>>(P.h2, norm_g, norm_b, fc2_w, fc2_b, (float*)d_out);
}

// Round 20
// 735.085 us; speedup vs baseline: 1.0102x; 1.0102x over previous
//
#include <hip/hip_runtime.h>
#include <math.h>

// ---------------- constants ----------------
#define NTOK   8192
#define INDIM  1024
#define NHEAD  8
#define N1     8282      // tokens incl cls (91*91 + 1)
#define NP     8448      // padded token count inside attention
#define PAD    166
#define LCH    33        // tokens per landmark chunk
#define SCALE  0.125f
#define HS     91
#define KS3    33        // split-K for fused S3/PV flash kernel
#define KC3    (NP / KS3)   // 256 tokens per block (4 chunks of 64)

typedef __attribute__((ext_vector_type(8))) _Float16 half8;
typedef __attribute__((ext_vector_type(8))) short short8;
typedef __attribute__((ext_vector_type(4))) float f32x4;
typedef unsigned short ushort_t;

#define GPTR(p) ((const __attribute__((address_space(1))) void*)(p))
#define LPTR(p) ((__attribute__((address_space(3))) void*)(p))

__device__ __forceinline__ ushort_t f2h(float f) {
    union { _Float16 h; ushort_t u; } v; v.h = (_Float16)f;
    return v.u;
}
__device__ __forceinline__ float h2f(ushort_t u) {
    union { ushort_t u; _Float16 h; } v; v.u = u;
    return (float)v.h;
}

// LDS chunk swizzle (validated R14): slot (row,c) holds logical chunk
// c ^ ((row>>1)&3); store side XORs the GLOBAL chunk, read side XORs the
// read chunk. Both per-thread compile-time constants.

// ---------------- reduce helpers (256-thread blocks) ----------------
__device__ __forceinline__ float blockReduceSumF(float v, float* red, int tid) {
    red[tid] = v; __syncthreads();
    for (int s = 128; s > 0; s >>= 1) {
        if (tid < s) red[tid] += red[tid + s];
        __syncthreads();
    }
    float r = red[0]; __syncthreads();
    return r;
}
__device__ __forceinline__ float blockReduceMaxF(float v, float* red, int tid) {
    red[tid] = v; __syncthreads();
    for (int s = 128; s > 0; s >>= 1) {
        if (tid < s) red[tid] = fmaxf(red[tid], red[tid + s]);
        __syncthreads();
    }
    float r = red[0]; __syncthreads();
    return r;
}

// ---------------- zero a float region (float4/thread) ----------------
__global__ void zero_k(float* __restrict__ p)
{
    int i = blockIdx.x * 256 + threadIdx.x;
    reinterpret_cast<float4*>(p)[i] = make_float4(0.f, 0.f, 0.f, 0.f);
}

// ---------------- weight transpose+cast: wT[n][k] = fp16(w[k][n]) ----------------
__global__ __launch_bounds__(256) void tcast_k(const float* __restrict__ w, ushort_t* __restrict__ wT,
                                               int K, int N)
{
    __shared__ float tb[32][33];
    int tx = threadIdx.x & 31, ty = threadIdx.x >> 5;
    int n0 = blockIdx.x * 32, k0 = blockIdx.y * 32;
#pragma unroll
    for (int i = 0; i < 4; ++i)
        tb[ty + i * 8][tx] = w[(size_t)(k0 + ty + i * 8) * N + n0 + tx];
    __syncthreads();
#pragma unroll
    for (int i = 0; i < 4; ++i)
        wT[(size_t)(n0 + ty + i * 8) * K + k0 + tx] = f2h(tb[tx][ty + i * 8]);
}

// ---------------- cast f32 -> fp16 (4 els/thread) ----------------
__global__ void bcast_k(const float* __restrict__ x, ushort_t* __restrict__ o)
{
    int i = blockIdx.x * 256 + threadIdx.x;
    float4 v = reinterpret_cast<const float4*>(x)[i];
    ushort4 u;
    u.x = f2h(v.x); u.y = f2h(v.y); u.z = f2h(v.z); u.w = f2h(v.w);
    reinterpret_cast<ushort4*>(o)[i] = u;
}

// ---------------- fp16 MFMA GEMM, 128x64 tile (M x N): out = [res +] A@B [+ bias] [relu] ----
__global__ __launch_bounds__(256) void gemm_mn_f16(
    const ushort_t* __restrict__ A, const ushort_t* __restrict__ BT,
    const float* __restrict__ bias, const float* __restrict__ res,
    float* __restrict__ C, ushort_t* __restrict__ Ch,
    int Mvalid, int K, int lda, int ldb, int ldc, int relu, int qscale)
{
    __shared__ ushort_t As[128 * 32];
    __shared__ ushort_t Bs[64 * 32];
    const int tid = threadIdx.x;
    const int wave = tid >> 6, lane = tid & 63;
    const int row0 = blockIdx.y * 128, col0 = blockIdx.x * 64;
    const int wr = wave * 32;
    const int aRow = wave * 16 + (lane >> 2);
    const int aChS = (((lane & 3) ^ ((lane >> 3) & 3)) * 8);
    const int bRow = tid >> 2;
    const int bChS = (((tid & 3) ^ ((tid >> 3) & 3)) * 8);
    const int lr = lane & 15, lq = (lane >> 4) * 4;
    const int lks = (((lane >> 4) ^ ((lr >> 1) & 3)) * 8);
    f32x4 acc[2][4] = {};
    for (int k0 = 0; k0 < K; k0 += 32) {
        __syncthreads();
#pragma unroll
        for (int i = 0; i < 2; ++i) {
            const ushort_t* gp = A + (size_t)(row0 + i * 64 + aRow) * lda + k0 + aChS;
            __builtin_amdgcn_global_load_lds(GPTR(gp), LPTR(As + (i * 64 + wave * 16) * 32), 16, 0, 0);
        }
        const ushort_t* gq = BT + (size_t)(col0 + bRow) * ldb + k0 + bChS;
        __builtin_amdgcn_global_load_lds(GPTR(gq), LPTR(Bs + tid * 8), 16, 0, 0);
        __syncthreads();
        half8 af[2], bfr[4];
#pragma unroll
        for (int mi = 0; mi < 2; ++mi)
            af[mi] = *reinterpret_cast<const half8*>(&As[(wr + mi * 16 + lr) * 32 + lks]);
#pragma unroll
        for (int ni = 0; ni < 4; ++ni)
            bfr[ni] = *reinterpret_cast<const half8*>(&Bs[(ni * 16 + lr) * 32 + lks]);
#pragma unroll
        for (int mi = 0; mi < 2; ++mi)
#pragma unroll
            for (int ni = 0; ni < 4; ++ni)
                acc[mi][ni] = __builtin_amdgcn_mfma_f32_16x16x32_f16(af[mi], bfr[ni], acc[mi][ni], 0, 0, 0);
    }
#pragma unroll
    for (int mi = 0; mi < 2; ++mi) {
#pragma unroll
        for (int q = 0; q < 4; ++q) {
            int r = row0 + wr + mi * 16 + lq + q;
            if (r >= Mvalid) continue;
#pragma unroll
            for (int ni = 0; ni < 4; ++ni) {
                int c = col0 + ni * 16 + lr;
                float v = acc[mi][ni][q];
                if (bias) v += bias[c];
                if (res)  v += res[(size_t)r * ldc + c];
                if (relu) v = fmaxf(v, 0.f);
                if (Ch) {
                    if (qscale && c < 512) v *= SCALE;
                    Ch[(size_t)r * ldc + c] = f2h(v);
                } else {
                    C[(size_t)r * ldc + c] = v;
                }
            }
        }
    }
}

// ---------------- batched fp16 MFMA 256^3, 64x64 tiles: C = diag*I + ss*(A@B) ----------------
__global__ __launch_bounds__(256) void bgemm64_f16(
    const ushort_t* __restrict__ A, const ushort_t* __restrict__ B,
    ushort_t* __restrict__ C, float diag, float ss,
    ushort_t* __restrict__ C2, float diag2, float ss2)
{
    __shared__ ushort_t As[64 * 32];
    __shared__ ushort_t Bs[64 * 32];
    const int h = blockIdx.z;
    const ushort_t* Ah = A + (size_t)h * 65536;
    const ushort_t* Bh = B + (size_t)h * 65536;
    const int tid = threadIdx.x;
    const int wave = tid >> 6, lane = tid & 63;
    const int row0 = blockIdx.y * 64, col0 = blockIdx.x * 64;
    const int wr = (wave >> 1) * 32, wc = (wave & 1) * 32;
    const int aRow = tid >> 2;
    const int aChS = (((tid & 3) ^ ((tid >> 3) & 3)) * 8);
    const int kp = (tid >> 3) & 15, nc = tid & 7;
    const int kk = (kp * 2) ^ ((nc & 3) << 3);
    const int lr = lane & 15, lk = (lane >> 4) * 8, lq = (lane >> 4) * 4;
    const int lks = (((lane >> 4) ^ ((lr >> 1) & 3)) * 8);
    f32x4 acc[2][2] = {};
    for (int k0 = 0; k0 < 256; k0 += 32) {
        __syncthreads();
        const ushort_t* gp = Ah + (size_t)(row0 + aRow) * 256 + k0 + aChS;
        __builtin_amdgcn_global_load_lds(GPTR(gp), LPTR(As + tid * 8), 16, 0, 0);
        if (tid < 128) {
            const ushort_t* bp = Bh + (size_t)(k0 + kp * 2) * 256 + col0 + nc * 8;
            short8 v0 = *reinterpret_cast<const short8*>(bp);
            short8 v1 = *reinterpret_cast<const short8*>(bp + 256);
#pragma unroll
            for (int j = 0; j < 8; ++j) {
                unsigned int pk = ((unsigned int)(ushort_t)v1[j] << 16) | (unsigned int)(ushort_t)v0[j];
                *reinterpret_cast<unsigned int*>(&Bs[(nc * 8 + j) * 32 + kk]) = pk;
            }
        }
        __syncthreads();
        half8 af[2], bfr[2];
#pragma unroll
        for (int mi = 0; mi < 2; ++mi)
            af[mi] = *reinterpret_cast<const half8*>(&As[(wr + mi * 16 + lr) * 32 + lks]);
#pragma unroll
        for (int ni = 0; ni < 2; ++ni) {
            int nn = wc + ni * 16 + lr;
            bfr[ni] = *reinterpret_cast<const half8*>(&Bs[nn * 32 + (lk ^ (((nn >> 3) & 3) << 3))]);
        }
#pragma unroll
        for (int mi = 0; mi < 2; ++mi)
#pragma unroll
            for (int ni = 0; ni < 2; ++ni)
                acc[mi][ni] = __builtin_amdgcn_mfma_f32_16x16x32_f16(af[mi], bfr[ni], acc[mi][ni], 0, 0, 0);
    }
    ushort_t* Chp = C + (size_t)h * 65536;
#pragma unroll
    for (int mi = 0; mi < 2; ++mi)
#pragma unroll
        for (int ni = 0; ni < 2; ++ni)
#pragma unroll
            for (int q = 0; q < 4; ++q) {
                int r = row0 + wr + mi * 16 + lq + q;
                int c = col0 + wc + ni * 16 + lr;
                float v = ss * acc[mi][ni][q];
                if (r == c) v += diag;
                Chp[(size_t)r * 256 + c] = f2h(v);
                if (C2) {
                    float v2 = ss2 * acc[mi][ni][q];
                    if (r == c) v2 += diag2;
                    C2[(size_t)h * 65536 + (size_t)r * 256 + c] = f2h(v2);
                }
            }
}

// ---------------- fused S3/PV flash kernel ----------------
// part[ks][h*256+r][d] = sum_{t in ks-range} exp(ql[r]·K[t]) V[t][d]; rsum atomically.
// grid (KS3, 2, 8). ql staged once; per 64-token chunk: S-tile MFMA -> exp -> Pl -> PV MFMA.
__global__ __launch_bounds__(256) void fs3_k(
    const ushort_t* __restrict__ ql, const ushort_t* __restrict__ qkv16,
    float* __restrict__ part, float* __restrict__ rsum)
{
    __shared__ ushort_t Qs[2][128 * 32];   // ql tile, two 32-k halves
    __shared__ ushort_t Bs[64 * 32];
    __shared__ ushort_t Pl[128][72];       // exp(S) chunk (144B row stride: aligned, 2-way banks)
    const int ks = blockIdx.x, row0 = blockIdx.y * 128, h = blockIdx.z;
    const ushort_t* Ah = ql + (size_t)h * 16384;
    const ushort_t* Kh = qkv16 + 512 + h * 64;
    const ushort_t* Vh = qkv16 + 1024 + h * 64;
    const int tid = threadIdx.x;
    const int wave = tid >> 6, lane = tid & 63;
    const int wr = wave * 32;
    const int aRow = wave * 16 + (lane >> 2);
    const int aChS = (((lane & 3) ^ ((lane >> 3) & 3)) * 8);
    const int bRow = tid >> 2;
    const int bChS = (((tid & 3) ^ ((tid >> 3) & 3)) * 8);
    const int lr = lane & 15, lk = (lane >> 4) * 8, lq = (lane >> 4) * 4;
    const int lks = (((lane >> 4) ^ ((lr >> 1) & 3)) * 8);
    const int kp = (tid >> 3) & 15, nc = tid & 7;
    const int kk = (kp * 2) ^ ((nc & 3) << 3);
    // stage ql tile once (both 32-k halves)
#pragma unroll
    for (int hh = 0; hh < 2; ++hh)
#pragma unroll
        for (int i = 0; i < 2; ++i) {
            const ushort_t* gp = Ah + (size_t)(row0 + i * 64 + aRow) * 64 + hh * 32 + aChS;
            __builtin_amdgcn_global_load_lds(GPTR(gp), LPTR(Qs[hh] + (i * 64 + wave * 16) * 32), 16, 0, 0);
        }
    f32x4 aco[2][4] = {};
    float rs[2][4] = {};
    for (int c = 0; c < KC3; c += 64) {
        const int tok0 = ks * KC3 + c;
        // ---- S-tile: exp(ql @ K_chunk^T) ----
        f32x4 acs[2][4] = {};
#pragma unroll
        for (int k0 = 0; k0 < 64; k0 += 32) {
            __syncthreads();
            const ushort_t* gq = Kh + (size_t)(tok0 + bRow) * 1536 + k0 + bChS;
            __builtin_amdgcn_global_load_lds(GPTR(gq), LPTR(Bs + tid * 8), 16, 0, 0);
            __syncthreads();
            half8 af[2], bfr[4];
#pragma unroll
            for (int mi = 0; mi < 2; ++mi)
                af[mi] = *reinterpret_cast<const half8*>(&Qs[k0 >> 5][(wr + mi * 16 + lr) * 32 + lks]);
#pragma unroll
            for (int ni = 0; ni < 4; ++ni)
                bfr[ni] = *reinterpret_cast<const half8*>(&Bs[(ni * 16 + lr) * 32 + lks]);
#pragma unroll
            for (int mi = 0; mi < 2; ++mi)
#pragma unroll
                for (int ni = 0; ni < 4; ++ni)
                    acs[mi][ni] = __builtin_amdgcn_mfma_f32_16x16x32_f16(af[mi], bfr[ni], acs[mi][ni], 0, 0, 0);
        }
        // exp -> Pl + row sums
#pragma unroll
        for (int mi = 0; mi < 2; ++mi)
#pragma unroll
            for (int q = 0; q < 4; ++q) {
                int r = wr + mi * 16 + lq + q;
                float s = 0.f;
#pragma unroll
                for (int ni = 0; ni < 4; ++ni) {
                    float e = __expf(acs[mi][ni][q]);
                    Pl[r][ni * 16 + lr] = f2h(e);
                    s += e;
                }
                for (int off = 8; off; off >>= 1) s += __shfl_xor(s, off, 64);
                rs[mi][q] += s;
            }
        // ---- PV: aco += Pl @ V_chunk ----
#pragma unroll
        for (int k0 = 0; k0 < 64; k0 += 32) {
            __syncthreads();
            if (tid < 128) {
                const ushort_t* bp = Vh + (size_t)(tok0 + k0 + kp * 2) * 1536 + nc * 8;
                short8 v0 = *reinterpret_cast<const short8*>(bp);
                short8 v1 = *reinterpret_cast<const short8*>(bp + 1536);
#pragma unroll
                for (int j = 0; j < 8; ++j) {
                    unsigned int pk = ((unsigned int)(ushort_t)v1[j] << 16) | (unsigned int)(ushort_t)v0[j];
                    *reinterpret_cast<unsigned int*>(&Bs[(nc * 8 + j) * 32 + kk]) = pk;
                }
            }
            __syncthreads();
            half8 af[2], bfr[4];
#pragma unroll
            for (int mi = 0; mi < 2; ++mi)
                af[mi] = *reinterpret_cast<const half8*>(&Pl[wr + mi * 16 + lr][k0 + lk]);
#pragma unroll
            for (int ni = 0; ni < 4; ++ni) {
                int nn = ni * 16 + lr;
                bfr[ni] = *reinterpret_cast<const half8*>(&Bs[nn * 32 + (lk ^ (((nn >> 3) & 3) << 3))]);
            }
#pragma unroll
            for (int mi = 0; mi < 2; ++mi)
#pragma unroll
                for (int ni = 0; ni < 4; ++ni)
                    aco[mi][ni] = __builtin_amdgcn_mfma_f32_16x16x32_f16(af[mi], bfr[ni], aco[mi][ni], 0, 0, 0);
        }
    }
    // write partials + rsum atomics
    float* pp = part + (size_t)(ks * 8 + h) * 16384;   // 256*64
#pragma unroll
    for (int mi = 0; mi < 2; ++mi)
#pragma unroll
        for (int q = 0; q < 4; ++q) {
            int r = row0 + wr + mi * 16 + lq + q;
#pragma unroll
            for (int ni = 0; ni < 4; ++ni)
                pp[(size_t)r * 64 + ni * 16 + lr] = aco[mi][ni][q];
            if (lr == 0) atomicAdd(&rsum[h * 256 + r], rs[mi][q]);
        }
}

__global__ __launch_bounds__(256) void pv_reduce_k(const float* __restrict__ part,
                                                   const float* __restrict__ rsum,
                                                   ushort_t* __restrict__ av)
{
    int idx = blockIdx.x * 256 + threadIdx.x;   // 131072
    int rc = idx >> 6;
    float s = 0.f;
#pragma unroll
    for (int ks = 0; ks < KS3; ++ks)
        s += part[(size_t)ks * 131072 + idx];
    av[idx] = f2h(s / rsum[rc]);
}

// ---------------- fused a1 path: attn = softmax(q @ kl^T) @ W ----------------
__global__ __launch_bounds__(256) void fa1_k(
    const ushort_t* __restrict__ qkv16, const ushort_t* __restrict__ kl,
    const ushort_t* __restrict__ W, ushort_t* __restrict__ attn)
{
    __shared__ ushort_t Pl[128][264];
    __shared__ ushort_t As[128 * 32];
    __shared__ ushort_t Bs[64 * 32];
    __shared__ float rs_l[128];
    const int h = blockIdx.y;
    const int row0 = blockIdx.x * 128;
    const ushort_t* Aq = qkv16 + h * 64;
    const ushort_t* klh = kl + (size_t)h * 16384;
    const ushort_t* Wh = W + (size_t)h * 16384;
    const int tid = threadIdx.x;
    const int wave = tid >> 6, lane = tid & 63;
    const int wr = wave * 32;
    const int aRow = wave * 16 + (lane >> 2);
    const int aChS = (((lane & 3) ^ ((lane >> 3) & 3)) * 8);
    const int bRow = tid >> 2;
    const int bChS = (((tid & 3) ^ ((tid >> 3) & 3)) * 8);
    const int lr = lane & 15, lk = (lane >> 4) * 8, lq = (lane >> 4) * 4;
    const int lks = (((lane >> 4) ^ ((lr >> 1) & 3)) * 8);
    const int kp = (tid >> 3) & 15, ncs = tid & 7;
    const int kk = (kp * 2) ^ ((ncs & 3) << 3);
    float rs[2][4] = {};
    for (int nc0 = 0; nc0 < 256; nc0 += 64) {
        f32x4 acc[2][4] = {};
        for (int k0 = 0; k0 < 64; k0 += 32) {
            __syncthreads();
#pragma unroll
            for (int i = 0; i < 2; ++i) {
                const ushort_t* gp = Aq + (size_t)(row0 + i * 64 + aRow) * 1536 + k0 + aChS;
                __builtin_amdgcn_global_load_lds(GPTR(gp), LPTR(As + (i * 64 + wave * 16) * 32), 16, 0, 0);
            }
            const ushort_t* gq = klh + (size_t)(nc0 + bRow) * 64 + k0 + bChS;
            __builtin_amdgcn_global_load_lds(GPTR(gq), LPTR(Bs + tid * 8), 16, 0, 0);
            __syncthreads();
            half8 af[2], bfr[4];
#pragma unroll
            for (int mi = 0; mi < 2; ++mi)
                af[mi] = *reinterpret_cast<const half8*>(&As[(wr + mi * 16 + lr) * 32 + lks]);
#pragma unroll
            for (int ni = 0; ni < 4; ++ni)
                bfr[ni] = *reinterpret_cast<const half8*>(&Bs[(ni * 16 + lr) * 32 + lks]);
#pragma unroll
            for (int mi = 0; mi < 2; ++mi)
#pragma unroll
                for (int ni = 0; ni < 4; ++ni)
                    acc[mi][ni] = __builtin_amdgcn_mfma_f32_16x16x32_f16(af[mi], bfr[ni], acc[mi][ni], 0, 0, 0);
        }
#pragma unroll
        for (int mi = 0; mi < 2; ++mi)
#pragma unroll
            for (int q = 0; q < 4; ++q) {
                int r = wr + mi * 16 + lq + q;
                float s = 0.f;
#pragma unroll
                for (int ni = 0; ni < 4; ++ni) {
                    float e = __expf(acc[mi][ni][q]);
                    Pl[r][nc0 + ni * 16 + lr] = f2h(e);
                    s += e;
                }
                for (int off = 8; off; off >>= 1) s += __shfl_xor(s, off, 64);
                rs[mi][q] += s;
            }
    }
    if (lr == 0) {
#pragma unroll
        for (int mi = 0; mi < 2; ++mi)
#pragma unroll
            for (int q = 0; q < 4; ++q)
                rs_l[wr + mi * 16 + lq + q] = rs[mi][q];
    }
    __syncthreads();
    f32x4 acc[2][4] = {};
    for (int k0 = 0; k0 < 256; k0 += 32) {
        __syncthreads();
        if (tid < 128) {
            const ushort_t* bp = Wh + (size_t)(k0 + kp * 2) * 64 + ncs * 8;
            short8 v0 = *reinterpret_cast<const short8*>(bp);
            short8 v1 = *reinterpret_cast<const short8*>(bp + 64);
#pragma unroll
            for (int j = 0; j < 8; ++j) {
                unsigned int pk = ((unsigned int)(ushort_t)v1[j] << 16) | (unsigned int)(ushort_t)v0[j];
                *reinterpret_cast<unsigned int*>(&Bs[(ncs * 8 + j) * 32 + kk]) = pk;
            }
        }
        __syncthreads();
        half8 af[2], bfr[4];
#pragma unroll
        for (int mi = 0; mi < 2; ++mi)
            af[mi] = *reinterpret_cast<const half8*>(&Pl[wr + mi * 16 + lr][k0 + lk]);
#pragma unroll
        for (int ni = 0; ni < 4; ++ni) {
            int nn = ni * 16 + lr;
            bfr[ni] = *reinterpret_cast<const half8*>(&Bs[nn * 32 + (lk ^ (((nn >> 3) & 3) << 3))]);
        }
#pragma unroll
        for (int mi = 0; mi < 2; ++mi)
#pragma unroll
            for (int ni = 0; ni < 4; ++ni)
                acc[mi][ni] = __builtin_amdgcn_mfma_f32_16x16x32_f16(af[mi], bfr[ni], acc[mi][ni], 0, 0, 0);
    }
#pragma unroll
    for (int mi = 0; mi < 2; ++mi)
#pragma unroll
        for (int q = 0; q < 4; ++q) {
            int rloc = wr + mi * 16 + lq + q;
            int t = row0 + rloc;
            float inv = 1.f / rs_l[rloc];
#pragma unroll
            for (int ni = 0; ni < 4; ++ni)
                attn[(size_t)t * 512 + h * 64 + ni * 16 + lr] = f2h(acc[mi][ni][q] * inv);
        }
}

// ---------------- W = z @ av (per head 256x256 @ 256x64), fp16, 4 rows/block ----------------
__global__ __launch_bounds__(256) void wmat_k(const ushort_t* __restrict__ z,
                                              const ushort_t* __restrict__ av,
                                              ushort_t* __restrict__ W)
{
    int idx = blockIdx.x * 4 + (threadIdx.x >> 6);
    int h = idx >> 8, m = idx & 255, d = threadIdx.x & 63;
    const ushort_t* zp = z + (size_t)h * 65536 + (size_t)m * 256;
    const ushort_t* ap = av + (size_t)h * 16384 + d;
    float acc = 0.f;
    for (int j = 0; j < 256; ++j) acc += h2f(zp[j]) * h2f(ap[(size_t)j * 64]);
    W[((size_t)h * 256 + m) * 64 + d] = f2h(acc);
}

// ---------------- fixup: cls token + wrap rows ----------------
__global__ void fixup_k(const float* __restrict__ cls, float* __restrict__ h)
{
    int i = blockIdx.x * 256 + threadIdx.x;
    if (i < 512) {
        h[i] = cls[i];
    } else {
        int j = i - 512;
        h[(size_t)8193 * 512 + j] = h[512 + j];
    }
}

// ---------------- layernorm + front zero-pad: out[NP][512] fp16 ----------------
__global__ __launch_bounds__(256) void ln_pad_k(
    const float* __restrict__ h, const float* __restrict__ g, const float* __restrict__ b,
    ushort_t* __restrict__ out)
{
    int row = blockIdx.x, tid = threadIdx.x;
    __shared__ float red[256];
    ushort_t* o = out + (size_t)row * 512;
    if (row < PAD) { o[tid] = 0; o[tid + 256] = 0; return; }
    const float* x = h + (size_t)(row - PAD) * 512;
    float v0 = x[tid], v1 = x[tid + 256];
    float mu = blockReduceSumF(v0 + v1, red, tid) * (1.f / 512.f);
    float d0 = v0 - mu, d1 = v1 - mu;
    float var = blockReduceSumF(d0 * d0 + d1 * d1, red, tid) * (1.f / 512.f);
    float rstd = rsqrtf(var + 1e-5f);
    o[tid]       = f2h(d0 * rstd * g[tid] + b[tid]);
    o[tid + 256] = f2h(d1 * rstd * g[tid + 256] + b[tid + 256]);
}

// ---------------- landmark means (q already pre-scaled), 4 (h,m) pairs/block ----------------
__global__ __launch_bounds__(256) void landmark_k(const ushort_t* __restrict__ qkv,
                                                  ushort_t* __restrict__ ql,
                                                  ushort_t* __restrict__ kl)
{
    int idx = blockIdx.x * 4 + (threadIdx.x >> 6);
    int h = idx >> 8, m = idx & 255, d = threadIdx.x & 63;
    const ushort_t* base = qkv + (size_t)(m * LCH) * 1536 + h * 64 + d;
    float sq = 0.f, sk = 0.f;
    for (int i = 0; i < LCH; ++i) {
        sq += h2f(base[(size_t)i * 1536]);
        sk += h2f(base[(size_t)i * 1536 + 512]);
    }
    ql[((size_t)h * 256 + m) * 64 + d] = f2h(sq * (1.f / (float)LCH));
    kl[((size_t)h * 256 + m) * 64 + d] = f2h(sk * (1.f / (float)LCH));
}

// ---------------- a2 = softmax(ql @ kl^T), fp16 out ----------------
__global__ __launch_bounds__(256) void a2_k(
    const ushort_t* __restrict__ ql, const ushort_t* __restrict__ kl, ushort_t* __restrict__ a2)
{
    int h = blockIdx.x >> 8, r = blockIdx.x & 255, tid = threadIdx.x;
    __shared__ float qv[64]; __shared__ float red[256];
    if (tid < 64) qv[tid] = h2f(ql[((size_t)h * 256 + r) * 64 + tid]);
    __syncthreads();
    const ushort_t* kp = kl + ((size_t)h * 256 + tid) * 64;
    float dot = 0.f;
#pragma unroll
    for (int d = 0; d < 64; ++d) dot += qv[d] * h2f(kp[d]);
    float mx = blockReduceMaxF(dot, red, tid);
    float e = expf(dot - mx);
    float s = blockReduceSumF(e, red, tid);
    a2[((size_t)h * 256 + r) * 256 + tid] = f2h(e / s);
}

// ---------------- pinv init: col = 1 exactly (softmax rows), scal = 1/max(colsum) ----------------
__global__ __launch_bounds__(256) void colsum_k(const ushort_t* __restrict__ a2, float* __restrict__ cs)
{
    int h = blockIdx.x >> 8, c = blockIdx.x & 255;
    __shared__ float red[256];
    float v = fabsf(h2f(a2[(size_t)h * 65536 + (size_t)threadIdx.x * 256 + c]));
    float s = blockReduceSumF(v, red, threadIdx.x);
    if (!threadIdx.x) cs[blockIdx.x] = s;
}
__global__ __launch_bounds__(256) void pinv_scal_k(const float* __restrict__ cs, float* __restrict__ scal)
{
    int tid = threadIdx.x; __shared__ float red[256];
    float m2 = -1e30f;
    for (int i = tid; i < 2048; i += 256) m2 = fmaxf(m2, cs[i]);
    m2 = blockReduceMaxF(m2, red, tid);
    if (!tid) scal[0] = 1.f / m2;
}
__global__ __launch_bounds__(256) void zinit_k(const ushort_t* __restrict__ a2, const float* __restrict__ scal,
                                               ushort_t* __restrict__ z)
{
    int h = blockIdx.x >> 8, r = blockIdx.x & 255, c = threadIdx.x;
    z[(size_t)h * 65536 + (size_t)r * 256 + c] =
        f2h(h2f(a2[(size_t)h * 65536 + (size_t)c * 256 + r]) * scal[0]);
}

// ---------------- tiled depthwise 33-tap conv over tokens on v (fp16), added to fp16 attn ----------------
#define CTT 64
__global__ __launch_bounds__(256) void conv2_k(const ushort_t* __restrict__ qkv,
                                               const float* __restrict__ cw,
                                               ushort_t* __restrict__ attn)
{
    __shared__ float vt[CTT + 32][64];
    int t0 = blockIdx.x * CTT;
    int h = blockIdx.y;
    int tid = threadIdx.x;
    for (int s = tid; s < (CTT + 32) * 8; s += 256) {
        int row = s >> 3, q8 = s & 7;
        int tt = t0 - 16 + row;
        if (tt >= 0 && tt < NP) {
            short8 v = *reinterpret_cast<const short8*>(qkv + (size_t)tt * 1536 + 1024 + h * 64 + q8 * 8);
#pragma unroll
            for (int j = 0; j < 8; ++j) vt[row][q8 * 8 + j] = h2f((ushort_t)v[j]);
        } else {
#pragma unroll
            for (int j = 0; j < 8; ++j) vt[row][q8 * 8 + j] = 0.f;
        }
    }
    float w33[33];
#pragma unroll
    for (int j = 0; j < 33; ++j) w33[j] = cw[h * 33 + j];
    __syncthreads();
    int c = tid & 63, tr = tid >> 6;
    float win[48];
#pragma unroll
    for (int j = 0; j < 48; ++j) win[j] = vt[tr * 16 + j][c];
#pragma unroll
    for (int i = 0; i < 16; ++i) {
        float acc = 0.f;
#pragma unroll
        for (int j = 0; j < 33; ++j) acc += w33[j] * win[i + j];
        size_t idx = (size_t)(t0 + tr * 16 + i) * 512 + h * 64 + c;
        attn[idx] = f2h(h2f(attn[idx]) + acc);
    }
}

// ---------------- PPEG tiled: transposed f32 LDS [tok][ch], PCG=8, float4 reads ----------------
#define PTS  16
#define PIT  22
#define PITT (PIT*PIT)   // 484
#define PCG  8
#define PSTR 12
__global__ __launch_bounds__(256) void ppeg_tiled_k(
    const float* __restrict__ hin,
    const float* __restrict__ w7, const float* __restrict__ b7,
    const float* __restrict__ w5, const float* __restrict__ b5,
    const float* __restrict__ w3, const float* __restrict__ b3,
    float* __restrict__ hout)
{
    __shared__ float inb[PITT][PSTR];
    __shared__ float wcT[49][PCG];
    __shared__ float bs[PCG];
    int tid = threadIdx.x;
    int c0 = blockIdx.z * PCG;
    int ty0 = blockIdx.y * PTS, tx0 = blockIdx.x * PTS;
    if (blockIdx.x == 0 && blockIdx.y == 0 && tid < PCG)
        hout[c0 + tid] = hin[c0 + tid];
    for (int idx = tid; idx < PITT * 2; idx += 256) {
        int tok = idx >> 1, q = idx & 1;
        int gy = ty0 - 3 + tok / PIT, gx = tx0 - 3 + tok % PIT;
        float4 v = make_float4(0.f, 0.f, 0.f, 0.f);
        if (gy >= 0 && gy < HS && gx >= 0 && gx < HS)
            v = *reinterpret_cast<const float4*>(hin + (size_t)(1 + gy * HS + gx) * 512 + c0 + q * 4);
        *reinterpret_cast<float4*>(&inb[tok][q * 4]) = v;
    }
    for (int idx = tid; idx < PCG * 49; idx += 256) {
        int c = idx / 49, t = idx % 49;
        int ky = t / 7, kx = t % 7, dy = ky - 3, dx = kx - 3;
        float w = w7[(size_t)(c0 + c) * 49 + t];
        if (dy >= -2 && dy <= 2 && dx >= -2 && dx <= 2)
            w += w5[(size_t)(c0 + c) * 25 + (dy + 2) * 5 + (dx + 2)];
        if (dy >= -1 && dy <= 1 && dx >= -1 && dx <= 1)
            w += w3[(size_t)(c0 + c) * 9 + (dy + 1) * 3 + (dx + 1)];
        wcT[t][c] = w;
    }
    if (tid < PCG) bs[tid] = b7[c0 + tid] + b5[c0 + tid] + b3[c0 + tid];
    __syncthreads();
    int oy = tid >> 4, ox = tid & 15;
    int gy = ty0 + oy, gx = tx0 + ox;
    if (gy >= HS || gx >= HS) return;
    float acc[PCG];
    {
        const float* cp = &inb[(oy + 3) * PIT + ox + 3][0];
        float4 i0 = *reinterpret_cast<const float4*>(cp);
        float4 i1 = *reinterpret_cast<const float4*>(cp + 4);
        acc[0] = i0.x + bs[0]; acc[1] = i0.y + bs[1]; acc[2] = i0.z + bs[2]; acc[3] = i0.w + bs[3];
        acc[4] = i1.x + bs[4]; acc[5] = i1.y + bs[5]; acc[6] = i1.z + bs[6]; acc[7] = i1.w + bs[7];
    }
#pragma unroll
    for (int ky = 0; ky < 7; ++ky)
#pragma unroll
        for (int kx = 0; kx < 7; ++kx) {
            int t = ky * 7 + kx;
            const float* dp = &inb[(oy + ky) * PIT + ox + kx][0];
            float4 d0 = *reinterpret_cast<const float4*>(dp);
            float4 d1 = *reinterpret_cast<const float4*>(dp + 4);
            float4 w0 = *reinterpret_cast<const float4*>(&wcT[t][0]);
            float4 w1 = *reinterpret_cast<const float4*>(&wcT[t][4]);
            acc[0] += w0.x * d0.x; acc[1] += w0.y * d0.y;
            acc[2] += w0.z * d0.z; acc[3] += w0.w * d0.w;
            acc[4] += w1.x * d1.x; acc[5] += w1.y * d1.y;
            acc[6] += w1.z * d1.z; acc[7] += w1.w * d1.w;
        }
    float* out = hout + (size_t)(1 + gy * HS + gx) * 512 + c0;
    *reinterpret_cast<float4*>(out)     = make_float4(acc[0], acc[1], acc[2], acc[3]);
    *reinterpret_cast<float4*>(out + 4) = make_float4(acc[4], acc[5], acc[6], acc[7]);
}

// ---------------- final LN(row0) + fc2 + softmax + argmax ----------------
__global__ __launch_bounds__(256) void final_k(const float* __restrict__ h,
                                               const float* __restrict__ g, const float* __restrict__ bb,
                                               const float* __restrict__ w, const float* __restrict__ fb,
                                               float* __restrict__ out)
{
    __shared__ float red[256];
    int tid = threadIdx.x;
    float v0 = h[tid], v1 = h[tid + 256];
    float mu = blockReduceSumF(v0 + v1, red, tid) * (1.f / 512.f);
    float d0 = v0 - mu, d1 = v1 - mu;
    float var = blockReduceSumF(d0 * d0 + d1 * d1, red, tid) * (1.f / 512.f);
    float rstd = rsqrtf(var + 1e-5f);
    float e0 = d0 * rstd * g[tid] + bb[tid];
    float e1 = d1 * rstd * g[tid + 256] + bb[tid + 256];
    out[5 + tid] = e0;
    out[5 + 256 + tid] = e1;
    float l0p = e0 * w[tid * 2] + e1 * w[(tid + 256) * 2];
    float l1p = e0 * w[tid * 2 + 1] + e1 * w[(tid + 256) * 2 + 1];
    float l0 = blockReduceSumF(l0p, red, tid);
    float l1 = blockReduceSumF(l1p, red, tid);
    if (!tid) {
        l0 += fb[0]; l1 += fb[1];
        out[0] = l0; out[1] = l1;
        float mx = fmaxf(l0, l1);
        float p0 = expf(l0 - mx), p1 = expf(l1 - mx);
        float si = 1.f / (p0 + p1);
        out[2] = p0 * si; out[3] = p1 * si;
        out[4] = (l1 > l0) ? 1.f : 0.f;
    }
}

// ---------------- host orchestration ----------------
struct WsPtrs {
    float *h, *h2, *cs, *scal, *rsum3, *part;
    ushort_t *xbB, *qkv16, *ql16, *kl16, *a2h, *zh, *z2h, *xzh, *t1h, *t2h;
    ushort_t *av16, *W16, *qkvT, *outT, *x16, *fc1T, *S16;
};

static void run_attn(float* hbuf, const float* ln_g, const float* ln_b,
                     const float* qkv_w, const float* out_w, const float* out_b,
                     const float* conv_w, const WsPtrs& P, hipStream_t s)
{
    tcast_k<<<dim3(1536 / 32, 512 / 32), 256, 0, s>>>(qkv_w, P.qkvT, 512, 1536);
    tcast_k<<<dim3(512 / 32, 512 / 32), 256, 0, s>>>(out_w, P.outT, 512, 512);
    ln_pad_k<<<NP, 256, 0, s>>>(hbuf, ln_g, ln_b, P.xbB);
    gemm_mn_f16<<<dim3(1536 / 64, NP / 128), 256, 0, s>>>(P.xbB, P.qkvT, nullptr, nullptr,
                                                          nullptr, P.qkv16, NP, 512, 512, 512, 1536, 0, 1);
    landmark_k<<<512, 256, 0, s>>>(P.qkv16, P.ql16, P.kl16);
    a2_k<<<2048, 256, 0, s>>>(P.ql16, P.kl16, P.a2h);
    colsum_k<<<2048, 256, 0, s>>>(P.a2h, P.cs);
    pinv_scal_k<<<1, 256, 0, s>>>(P.cs, P.scal);
    zinit_k<<<2048, 256, 0, s>>>(P.a2h, P.scal, P.zh);
    ushort_t* za = P.zh; ushort_t* zb = P.z2h;
    for (int it = 0; it < 6; ++it) {
        bgemm64_f16<<<dim3(4, 4, 8), 256, 0, s>>>(P.a2h, za, P.xzh, 0.f, 1.f, P.t1h, 7.f, -1.f);
        bgemm64_f16<<<dim3(4, 4, 8), 256, 0, s>>>(P.xzh, P.t1h, P.t2h, 15.f, -1.f, nullptr, 0.f, 0.f);
        bgemm64_f16<<<dim3(4, 4, 8), 256, 0, s>>>(P.xzh, P.t2h, P.t1h, 13.f, -1.f, nullptr, 0.f, 0.f);
        bgemm64_f16<<<dim3(4, 4, 8), 256, 0, s>>>(za, P.t1h, zb, 0.f, 0.25f, nullptr, 0.f, 0.f);
        ushort_t* tmp = za; za = zb; zb = tmp;
    }
    // zero rsum3 (2048 floats)
    zero_k<<<2, 256, 0, s>>>(P.rsum3);
    // av path: fused flash S3/PV -> reduce
    fs3_k<<<dim3(KS3, 2, 8), 256, 0, s>>>(P.ql16, P.qkv16, P.part, P.rsum3);
    pv_reduce_k<<<512, 256, 0, s>>>(P.part, P.rsum3, P.av16);
    wmat_k<<<512, 256, 0, s>>>(za, P.av16, P.W16);
    // a1 path: fully fused
    fa1_k<<<dim3(NP / 128, 8), 256, 0, s>>>(P.qkv16, P.kl16, P.W16, P.xbB);
    conv2_k<<<dim3(NP / CTT, 8), 256, 0, s>>>(P.qkv16, conv_w, P.xbB);
    gemm_mn_f16<<<dim3(512 / 64, (N1 + 127) / 128), 256, 0, s>>>(P.xbB + (size_t)PAD * 512, P.outT,
                                                                 out_b, hbuf, hbuf, nullptr,
                                                                 N1, 512, 512, 512, 512, 0, 0);
}

extern "C" void kernel_launch(void* const* d_in, const int* in_sizes, int n_in,
                              void* d_out, int out_size, void* d_ws, size_t ws_size,
                              hipStream_t stream)
{
    (void)in_sizes; (void)n_in; (void)out_size; (void)ws_size;
    const float* x       = (const float*)d_in[0];
    const float* fc1_w   = (const float*)d_in[1];
    const float* fc1_b   = (const float*)d_in[2];
    const float* cls_tok = (const float*)d_in[3];
    const float* ln1_g   = (const float*)d_in[4];
    const float* ln1_b   = (const float*)d_in[5];
    const float* qkv1_w  = (const float*)d_in[6];
    const float* out1_w  = (const float*)d_in[7];
    const float* out1_b  = (const float*)d_in[8];
    const float* conv1_w = (const float*)d_in[9];
    const float* ln2_g   = (const float*)d_in[10];
    const float* ln2_b   = (const float*)d_in[11];
    const float* qkv2_w  = (const float*)d_in[12];
    const float* out2_w  = (const float*)d_in[13];
    const float* out2_b  = (const float*)d_in[14];
    const float* conv2_w = (const float*)d_in[15];
    const float* pg7_w   = (const float*)d_in[16];
    const float* pg7_b   = (const float*)d_in[17];
    const float* pg5_w   = (const float*)d_in[18];
    const float* pg5_b   = (const float*)d_in[19];
    const float* pg3_w   = (const float*)d_in[20];
    const float* pg3_b   = (const float*)d_in[21];
    const float* norm_g  = (const float*)d_in[22];
    const float* norm_b  = (const float*)d_in[23];
    const float* fc2_w   = (const float*)d_in[24];
    const float* fc2_b   = (const float*)d_in[25];

    float* ws = (float*)d_ws;
    WsPtrs P;
    float* cur = ws;
    P.h     = cur; cur += (size_t)N1 * 512;
    P.h2    = cur; cur += (size_t)N1 * 512;
    P.xbB   = (ushort_t*)cur; cur += (size_t)NP * 512 / 2;
    P.qkv16 = (ushort_t*)cur; cur += (size_t)NP * 1536 / 2;
    P.ql16  = (ushort_t*)cur; cur += 65536;
    P.kl16  = (ushort_t*)cur; cur += 65536;
    P.a2h   = (ushort_t*)cur; cur += 262144;
    P.zh    = (ushort_t*)cur; cur += 262144;
    P.z2h   = (ushort_t*)cur; cur += 262144;
    P.xzh   = (ushort_t*)cur; cur += 262144;
    P.t1h   = (ushort_t*)cur; cur += 262144;
    P.t2h   = (ushort_t*)cur; cur += 262144;
    P.av16  = (ushort_t*)cur; cur += 65536;
    P.W16   = (ushort_t*)cur; cur += 65536;
    P.cs    = cur; cur += 2048;
    P.scal  = cur; cur += 64;
    P.qkvT  = (ushort_t*)cur; cur += 393216 + 64;   // 1536x512 halfs
    P.outT  = (ushort_t*)cur; cur += 131072 + 64;   // 512x512 halfs
    P.rsum3 = cur; cur += 2048;
    P.part  = cur; cur += (size_t)KS3 * 131072;
    P.S16   = (ushort_t*)cur; cur += (size_t)8 * 256 * NP / 2;   // used only for x16/fc1T prep
    P.x16   = P.S16;                                         // 8192x1024 halfs (alias, pre-S use)
    P.fc1T  = P.S16 + (size_t)NTOK * INDIM;                  // 512x1024 halfs

    bcast_k<<<(NTOK * INDIM) / 1024, 256, 0, stream>>>(x, P.x16);
    tcast_k<<<dim3(512 / 32, 1024 / 32), 256, 0, stream>>>(fc1_w, P.fc1T, 1024, 512);
    gemm_mn_f16<<<dim3(512 / 64, NTOK / 128), 256, 0, stream>>>(P.x16, P.fc1T, fc1_b, nullptr,
                                                                P.h + 512, nullptr,
                                                                NTOK, 1024, 1024, 1024, 512, 1, 0);
    fixup_k<<<180, 256, 0, stream>>>(cls_tok, P.h);
    run_attn(P.h, ln1_g, ln1_b, qkv1_w, out1_w, out1_b, conv1_w, P, stream);
    ppeg_tiled_k<<<dim3(6, 6, 512 / PCG), 256, 0, stream>>>(P.h, pg7_w, pg7_b, pg5_w, pg5_b,
                                                            pg3_w, pg3_b, P.h2);
    run_attn(P.h2, ln2_g, ln2_b, qkv2_w, out2_w, out2_b, conv2_w, P, stream);
    final_k<<<1, 256, 0, stream>>>(P.h2, norm_g, norm_b, fc2_w, fc2_b, (float*)d_out);
}